// Round 7
// baseline (59.390 us; speedup 1.0000x reference)
//
#include <hip/hip_runtime.h>
#include <math.h>

// YOLO loss: pred/target (4096,14,14,30) fp32 -> scalar.
// R6: R5 structure (32-cell tiles, 2 lanes/cell, dbuf global_load_lds with
// counted vmcnt, 8 waves/CU) + single-kernel last-block final reduction
// (device-scope fence + agent atomics) to remove the 2nd launch.

#define SGRID 14
#define NCLS 20
#define CELLS_PER_TILE 32
#define F4_PER_INPUT 240         // 32 cells * 30 floats / 4
#define TILE_F4 480              // both inputs
#define NT_TILES 25088           // 802816 cells / 32
#define NBLOCKS 512

constexpr float STEPF  = 1.0f / 14.0f;
constexpr float EPSF   = 1e-7f;
constexpr float L_COORD = 5.0f;
constexpr float L_NOOBJ = 0.5f;

__device__ __forceinline__ float waveSum(float v) {
#pragma unroll
    for (int o = 32; o > 0; o >>= 1) v += __shfl_down(v, o);
    return v;
}

__device__ __forceinline__ void gload_lds16(const void* gsrc, void* ldst) {
    __builtin_amdgcn_global_load_lds(
        (const __attribute__((address_space(1))) void*)gsrc,
        (__attribute__((address_space(3))) void*)ldst, 16, 0, 0);
}
__device__ __forceinline__ void gload_lds4(const void* gsrc, void* ldst) {
    __builtin_amdgcn_global_load_lds(
        (const __attribute__((address_space(1))) void*)gsrc,
        (__attribute__((address_space(3))) void*)ldst, 4, 0, 0);
}

// Stage one 32-cell tile (floats [0..959]=pred, [960..1919]=targ):
// 7 wave-loads of 16B + 2 wave-loads of 4B = 9 vmem ops.
__device__ __forceinline__ void issueTile(const float4* pred4, const float4* targ4,
                                          int tile, int l, float4* dst) {
    const float4* psrc = pred4 + (size_t)tile * F4_PER_INPUT;
    const float4* tsrc = targ4 + (size_t)tile * F4_PER_INPUT;
#pragma unroll
    for (int i = 0; i < 7; ++i) {
        int g = i * 64 + l;
        const float4* src = (g < F4_PER_INPUT) ? (psrc + g) : (tsrc + (g - F4_PER_INPUT));
        gload_lds16(src, dst + i * 64);
    }
    const float* tf = reinterpret_cast<const float*>(tsrc);
    float* df = reinterpret_cast<float*>(dst);
#pragma unroll
    for (int j = 0; j < 2; ++j) {
        gload_lds4(tf + 832 + j * 64 + l, df + 1792 + j * 64);
    }
}

__global__ __launch_bounds__(256, 2) void yolo_main(const float* __restrict__ pred,
                                                    const float* __restrict__ targ,
                                                    float* __restrict__ ws,
                                                    unsigned* __restrict__ counter,
                                                    float* __restrict__ out,
                                                    float invN) {
    __shared__ float4 stage[4][2][TILE_F4];   // 61440 B
    __shared__ float red[4][6];
    __shared__ int lastFlag;

    const int t = threadIdx.x;
    const int w = t >> 6;       // wave in block (0..3)
    const int l = t & 63;       // lane
    const int c = l >> 1;       // cell within tile (0..31)
    const int b = l & 1;        // box index this lane owns

    float s0 = 0.f, s1 = 0.f, s2 = 0.f, s3 = 0.f, s4 = 0.f, s5 = 0.f;

    const int G = gridDim.x * 4;
    const int gwave = blockIdx.x * 4 + w;

    const float4* pred4 = reinterpret_cast<const float4*>(pred);
    const float4* targ4 = reinterpret_cast<const float4*>(targ);

    int buf = 0;
    if (gwave < NT_TILES) issueTile(pred4, targ4, gwave, l, stage[w][0]);

    for (int tile = gwave; tile < NT_TILES; tile += G) {
        const int nxt = tile + G;
        if (nxt < NT_TILES) {
            asm volatile("s_waitcnt lgkmcnt(0)" ::: "memory");
            __builtin_amdgcn_sched_barrier(0);
            issueTile(pred4, targ4, nxt, l, stage[w][buf ^ 1]);
            // wait only for current tile's 9 loads; next tile's 9 stay in flight
            asm volatile("s_waitcnt vmcnt(9)" ::: "memory");
        } else {
            asm volatile("s_waitcnt vmcnt(0)" ::: "memory");
        }
        __builtin_amdgcn_sched_barrier(0);

        const float* P = reinterpret_cast<const float*>(stage[w][buf]);
        const float* T = P + 960;
        buf ^= 1;

        // ---- box phase: lane owns box b of cell c ----
        const float2* p2 = reinterpret_cast<const float2*>(P + 30 * c);
        const float2* t2 = reinterpret_cast<const float2*>(T + 30 * c);
        float2 pA = p2[2 * b], pB = p2[2 * b + 1], pC = p2[2 * b + 2];
        float2 tA = t2[2 * b], tB = t2[2 * b + 1], tC = t2[2 * b + 2];
        float t9v = (T + 30 * c)[9];
        float p0 = b ? pA.y : pA.x;
        float p1 = b ? pB.x : pA.y;
        float p2f = b ? pB.y : pB.x;
        float p3f = b ? pC.x : pB.y;
        float p4f = b ? pC.y : pC.x;
        float t0 = b ? tA.y : tA.x;
        float t1 = b ? tB.x : tA.y;
        float t2f = b ? tB.y : tB.x;
        float t3f = b ? tC.x : tB.y;
        float t4f = b ? tC.y : tC.x;

        int cell = tile * CELLS_PER_TILE + c;     // layout (n, jy, ix)
        float ix = (float)(cell % SGRID);
        float jy = (float)((cell / SGRID) % SGRID);

        // paired IOU (cell-converted) for argmax
        float px = fmaxf((p0 + ix) * STEPF - p2f * 0.5f, 0.f);
        float py = fmaxf((p1 + jy) * STEPF - p3f * 0.5f, 0.f);
        float pw = fmaxf(p2f, 0.f), ph = fmaxf(p3f, 0.f);
        float tx = fmaxf((t0 + ix) * STEPF - t2f * 0.5f, 0.f);
        float ty = fmaxf((t1 + jy) * STEPF - t3f * 0.5f, 0.f);
        float tw = fmaxf(t2f, 0.f), th = fmaxf(t3f, 0.f);
        float iw = pw + tw - (fmaxf(px + pw, tx + tw) - fminf(px, tx));
        float ih = ph + th - (fmaxf(py + ph, ty + th) - fminf(py, ty));
        float inter0 = fmaxf(iw, 0.f) * fmaxf(ih, 0.f);
        float iouP = inter0 / (pw * ph + tw * th - inter0 + EPSF);

        float other = __shfl_xor(iouP, 1);
        float i0 = b ? other : iouP;
        float i1 = b ? iouP : other;
        int maxi = (i1 > i0) ? 1 : 0;             // jnp.argmax: ties -> 0
        bool sig = t9v > 0.f;
        bool om = t4f > 0.f;
        bool kp = (!sig) || (b == maxi);
        float f = (om && kp) ? 1.f : 0.f;

        float d = p4f - t4f;
        float d2 = d * d;
        s0 += f * d2;
        s1 += (1.f - f) * d2;

        // DIoU on raw xywh -> xyxy
        float px1 = p0 - p2f * 0.5f, py1 = p1 - p3f * 0.5f;
        float px2 = p0 + p2f * 0.5f, py2 = p1 + p3f * 0.5f;
        float tx1 = t0 - t2f * 0.5f, ty1 = t1 - t3f * 0.5f;
        float tx2 = t0 + t2f * 0.5f, ty2 = t1 + t3f * 0.5f;

        float xi1 = fmaxf(px1, tx1), yi1 = fmaxf(py1, ty1);
        float xi2 = fminf(px2, tx2), yi2 = fminf(py2, ty2);
        float inter = fmaxf(xi2 - xi1, 0.f) * fmaxf(yi2 - yi1, 0.f);
        float a1 = fmaxf(px2 - px1, 0.f) * fmaxf(py2 - py1, 0.f);
        float a2 = fmaxf(tx2 - tx1, 0.f) * fmaxf(ty2 - ty1, 0.f);
        float iou = fmaxf(inter / (a1 + a2 - inter + EPSF), EPSF);

        float pcx = (px1 + px2) * 0.5f, pcy = (py1 + py2) * 0.5f;
        float tcx = (tx1 + tx2) * 0.5f, tcy = (ty1 + ty2) * 0.5f;
        float cd = (pcx - tcx) * (pcx - tcx) + (pcy - tcy) * (pcy - tcy);
        float ex1 = fminf(px1, tx1), ey1 = fminf(py1, ty1);
        float ex2 = fmaxf(px2, tx2), ey2 = fmaxf(py2, ty2);
        float diag = (ex2 - ex1) * (ex2 - ex1) + (ey2 - ey1) * (ey2 - ey1) + EPSF;
        float diou = 1.f - sqrtf(iou) + cd / diag;

        s2 += f * diou;
        s3 += f;

        // ---- class phase: lane handles 10 channels (10b..10b+9) of cell c ----
        const float2* pc2 = reinterpret_cast<const float2*>(P + 30 * c + 10 + 10 * b);
        const float2* tc2 = reinterpret_cast<const float2*>(T + 30 * c + 10 + 10 * b);
        float fs = 0.f;
#pragma unroll
        for (int m = 0; m < 5; ++m) {
            float2 a = pc2[m], e = tc2[m];
            float ce1 = a.x - e.x; ce1 *= ce1;
            float pt1 = fminf(fmaxf(__expf(-ce1), EPSF), 1.0f);
            float o1 = 1.f - pt1;
            fs += o1 * o1 * ce1;
            float ce2 = a.y - e.y; ce2 *= ce2;
            float pt2 = fminf(fmaxf(__expf(-ce2), EPSF), 1.0f);
            float o2 = 1.f - pt2;
            fs += o2 * o2 * ce2;
        }
        if (sig) {
            s4 += fs;
            if (b == 0) s5 += 1.f;
        }
    }

    // ---- block reduce: wave shuffle -> LDS across 4 waves ----
    float s[6] = { s0, s1, s2, s3, s4, s5 };
#pragma unroll
    for (int q = 0; q < 6; ++q) s[q] = waveSum(s[q]);
    if (l == 0) {
#pragma unroll
        for (int q = 0; q < 6; ++q) red[w][q] = s[q];
    }
    __syncthreads();
    if (t == 0) {
        float v[6];
#pragma unroll
        for (int q = 0; q < 6; ++q) v[q] = red[0][q] + red[1][q] + red[2][q] + red[3][q];
        float4* o = reinterpret_cast<float4*>(ws + (size_t)blockIdx.x * 8);
        o[0] = make_float4(v[0], v[1], v[2], v[3]);
        o[1] = make_float4(v[4], v[5], 0.f, 0.f);
        __threadfence();   // device-scope: make partials visible across XCDs
        unsigned old = __hip_atomic_fetch_add(counter, 1u, __ATOMIC_ACQ_REL,
                                              __HIP_MEMORY_SCOPE_AGENT);
        lastFlag = (old == (unsigned)(gridDim.x - 1)) ? 1 : 0;
    }
    __syncthreads();

    // ---- last block folds all 512 partials and writes the scalar ----
    if (lastFlag) {
        float r[6] = {0.f, 0.f, 0.f, 0.f, 0.f, 0.f};
        for (int row = t; row < NBLOCKS; row += 256) {
            const float* src = ws + (size_t)row * 8;
#pragma unroll
            for (int q = 0; q < 6; ++q)
                r[q] += __hip_atomic_load(&src[q], __ATOMIC_RELAXED,
                                          __HIP_MEMORY_SCOPE_AGENT);
        }
#pragma unroll
        for (int q = 0; q < 6; ++q) r[q] = waveSum(r[q]);
        if (l == 0) {
#pragma unroll
            for (int q = 0; q < 6; ++q) red[w][q] = r[q];
        }
        __syncthreads();
        if (t == 0) {
            float obj   = red[0][0] + red[1][0] + red[2][0] + red[3][0];
            float noobj = red[0][1] + red[1][1] + red[2][1] + red[3][1];
            float bboxS = red[0][2] + red[1][2] + red[2][2] + red[3][2];
            float nObj  = red[0][3] + red[1][3] + red[2][3] + red[3][3];
            float clsS  = red[0][4] + red[1][4] + red[2][4] + red[3][4];
            float smS   = red[0][5] + red[1][5] + red[2][5] + red[3][5];

            float bbox_loss = (nObj > 0.f) ? (bboxS / fmaxf(nObj, 1.f)) : 0.f;
            float nCls = smS * (float)NCLS;
            float class_loss = (nCls > 0.f) ? (clsS / fmaxf(nCls, 1.f)) : 0.f;
            float total = obj + L_NOOBJ * noobj + L_COORD * bbox_loss + class_loss;
            out[0] = total * invN;
        }
    }
}

extern "C" void kernel_launch(void* const* d_in, const int* in_sizes, int n_in,
                              void* d_out, int out_size, void* d_ws, size_t ws_size,
                              hipStream_t stream) {
    const float* pred = (const float*)d_in[0];
    const float* targ = (const float*)d_in[1];
    float* out = (float*)d_out;
    float* ws = (float*)d_ws;
    unsigned* counter = (unsigned*)((char*)d_ws + (size_t)NBLOCKS * 8 * sizeof(float));

    hipMemsetAsync(counter, 0, sizeof(unsigned), stream);
    yolo_main<<<NBLOCKS, 256, 0, stream>>>(pred, targ, ws, counter, out,
                                           1.0f / 4096.0f);
}

// Round 8
// 39.078 us; speedup vs baseline: 1.5198x; 1.5198x over previous
//
#include <hip/hip_runtime.h>
#include <math.h>

// YOLO loss: pred/target (4096,14,14,30) fp32 -> scalar.
// R7: R5 compute/staging (32-cell tiles, 2 lanes/cell, dbuf global_load_lds,
// counted vmcnt, two-kernel reduce) with 2-wave blocks @ 30.7KB LDS
// -> 5 blocks/CU = 10 waves/CU sustained memory concurrency.

#define SGRID 14
#define NCLS 20
#define CELLS_PER_TILE 32
#define F4_PER_INPUT 240         // 32 cells * 30 floats / 4
#define TILE_F4 480              // both inputs
#define NT_TILES 25088           // 802816 cells / 32
#define NBLOCKS 1280
#define WAVES 2

constexpr float STEPF  = 1.0f / 14.0f;
constexpr float EPSF   = 1e-7f;
constexpr float L_COORD = 5.0f;
constexpr float L_NOOBJ = 0.5f;

__device__ __forceinline__ float waveSum(float v) {
#pragma unroll
    for (int o = 32; o > 0; o >>= 1) v += __shfl_down(v, o);
    return v;
}

__device__ __forceinline__ void gload_lds16(const void* gsrc, void* ldst) {
    __builtin_amdgcn_global_load_lds(
        (const __attribute__((address_space(1))) void*)gsrc,
        (__attribute__((address_space(3))) void*)ldst, 16, 0, 0);
}
__device__ __forceinline__ void gload_lds4(const void* gsrc, void* ldst) {
    __builtin_amdgcn_global_load_lds(
        (const __attribute__((address_space(1))) void*)gsrc,
        (__attribute__((address_space(3))) void*)ldst, 4, 0, 0);
}

// Stage one 32-cell tile (floats [0..959]=pred, [960..1919]=targ):
// 7 wave-loads of 16B + 2 wave-loads of 4B = 9 vmem ops.
__device__ __forceinline__ void issueTile(const float4* pred4, const float4* targ4,
                                          int tile, int l, float4* dst) {
    const float4* psrc = pred4 + (size_t)tile * F4_PER_INPUT;
    const float4* tsrc = targ4 + (size_t)tile * F4_PER_INPUT;
#pragma unroll
    for (int i = 0; i < 7; ++i) {
        int g = i * 64 + l;
        const float4* src = (g < F4_PER_INPUT) ? (psrc + g) : (tsrc + (g - F4_PER_INPUT));
        gload_lds16(src, dst + i * 64);
    }
    const float* tf = reinterpret_cast<const float*>(tsrc);
    float* df = reinterpret_cast<float*>(dst);
#pragma unroll
    for (int j = 0; j < 2; ++j) {
        gload_lds4(tf + 832 + j * 64 + l, df + 1792 + j * 64);
    }
}

__global__ __launch_bounds__(128, 2) void yolo_main(const float* __restrict__ pred,
                                                    const float* __restrict__ targ,
                                                    float* __restrict__ ws) {
    __shared__ float4 stage[WAVES][2][TILE_F4];   // 30720 B -> 5 blocks/CU
    __shared__ float red[WAVES][6];

    const int t = threadIdx.x;
    const int w = t >> 6;       // wave in block (0..1)
    const int l = t & 63;       // lane
    const int c = l >> 1;       // cell within tile (0..31)
    const int b = l & 1;        // box index this lane owns

    float s0 = 0.f, s1 = 0.f, s2 = 0.f, s3 = 0.f, s4 = 0.f, s5 = 0.f;

    const int G = gridDim.x * WAVES;
    const int gwave = blockIdx.x * WAVES + w;

    const float4* pred4 = reinterpret_cast<const float4*>(pred);
    const float4* targ4 = reinterpret_cast<const float4*>(targ);

    int buf = 0;
    if (gwave < NT_TILES) issueTile(pred4, targ4, gwave, l, stage[w][0]);

    for (int tile = gwave; tile < NT_TILES; tile += G) {
        const int nxt = tile + G;
        if (nxt < NT_TILES) {
            asm volatile("s_waitcnt lgkmcnt(0)" ::: "memory");
            __builtin_amdgcn_sched_barrier(0);
            issueTile(pred4, targ4, nxt, l, stage[w][buf ^ 1]);
            // wait only for current tile's 9 loads; next tile's 9 stay in flight
            asm volatile("s_waitcnt vmcnt(9)" ::: "memory");
        } else {
            asm volatile("s_waitcnt vmcnt(0)" ::: "memory");
        }
        __builtin_amdgcn_sched_barrier(0);

        const float* P = reinterpret_cast<const float*>(stage[w][buf]);
        const float* T = P + 960;
        buf ^= 1;

        // ---- box phase: lane owns box b of cell c ----
        const float2* p2 = reinterpret_cast<const float2*>(P + 30 * c);
        const float2* t2 = reinterpret_cast<const float2*>(T + 30 * c);
        float2 pA = p2[2 * b], pB = p2[2 * b + 1], pC = p2[2 * b + 2];
        float2 tA = t2[2 * b], tB = t2[2 * b + 1], tC = t2[2 * b + 2];
        float t9v = (T + 30 * c)[9];
        float p0 = b ? pA.y : pA.x;
        float p1 = b ? pB.x : pA.y;
        float p2f = b ? pB.y : pB.x;
        float p3f = b ? pC.x : pB.y;
        float p4f = b ? pC.y : pC.x;
        float t0 = b ? tA.y : tA.x;
        float t1 = b ? tB.x : tA.y;
        float t2f = b ? tB.y : tB.x;
        float t3f = b ? tC.x : tB.y;
        float t4f = b ? tC.y : tC.x;

        int cell = tile * CELLS_PER_TILE + c;     // layout (n, jy, ix)
        float ix = (float)(cell % SGRID);
        float jy = (float)((cell / SGRID) % SGRID);

        // paired IOU (cell-converted) for argmax
        float px = fmaxf((p0 + ix) * STEPF - p2f * 0.5f, 0.f);
        float py = fmaxf((p1 + jy) * STEPF - p3f * 0.5f, 0.f);
        float pw = fmaxf(p2f, 0.f), ph = fmaxf(p3f, 0.f);
        float tx = fmaxf((t0 + ix) * STEPF - t2f * 0.5f, 0.f);
        float ty = fmaxf((t1 + jy) * STEPF - t3f * 0.5f, 0.f);
        float tw = fmaxf(t2f, 0.f), th = fmaxf(t3f, 0.f);
        float iw = pw + tw - (fmaxf(px + pw, tx + tw) - fminf(px, tx));
        float ih = ph + th - (fmaxf(py + ph, ty + th) - fminf(py, ty));
        float inter0 = fmaxf(iw, 0.f) * fmaxf(ih, 0.f);
        float iouP = inter0 / (pw * ph + tw * th - inter0 + EPSF);

        float other = __shfl_xor(iouP, 1);
        float i0 = b ? other : iouP;
        float i1 = b ? iouP : other;
        int maxi = (i1 > i0) ? 1 : 0;             // jnp.argmax: ties -> 0
        bool sig = t9v > 0.f;
        bool om = t4f > 0.f;
        bool kp = (!sig) || (b == maxi);
        float f = (om && kp) ? 1.f : 0.f;

        float d = p4f - t4f;
        float d2 = d * d;
        s0 += f * d2;
        s1 += (1.f - f) * d2;

        // DIoU on raw xywh -> xyxy
        float px1 = p0 - p2f * 0.5f, py1 = p1 - p3f * 0.5f;
        float px2 = p0 + p2f * 0.5f, py2 = p1 + p3f * 0.5f;
        float tx1 = t0 - t2f * 0.5f, ty1 = t1 - t3f * 0.5f;
        float tx2 = t0 + t2f * 0.5f, ty2 = t1 + t3f * 0.5f;

        float xi1 = fmaxf(px1, tx1), yi1 = fmaxf(py1, ty1);
        float xi2 = fminf(px2, tx2), yi2 = fminf(py2, ty2);
        float inter = fmaxf(xi2 - xi1, 0.f) * fmaxf(yi2 - yi1, 0.f);
        float a1 = fmaxf(px2 - px1, 0.f) * fmaxf(py2 - py1, 0.f);
        float a2 = fmaxf(tx2 - tx1, 0.f) * fmaxf(ty2 - ty1, 0.f);
        float iou = fmaxf(inter / (a1 + a2 - inter + EPSF), EPSF);

        float pcx = (px1 + px2) * 0.5f, pcy = (py1 + py2) * 0.5f;
        float tcx = (tx1 + tx2) * 0.5f, tcy = (ty1 + ty2) * 0.5f;
        float cd = (pcx - tcx) * (pcx - tcx) + (pcy - tcy) * (pcy - tcy);
        float ex1 = fminf(px1, tx1), ey1 = fminf(py1, ty1);
        float ex2 = fmaxf(px2, tx2), ey2 = fmaxf(py2, ty2);
        float diag = (ex2 - ex1) * (ex2 - ex1) + (ey2 - ey1) * (ey2 - ey1) + EPSF;
        float diou = 1.f - sqrtf(iou) + cd / diag;

        s2 += f * diou;
        s3 += f;

        // ---- class phase: lane handles 10 channels (10b..10b+9) of cell c ----
        const float2* pc2 = reinterpret_cast<const float2*>(P + 30 * c + 10 + 10 * b);
        const float2* tc2 = reinterpret_cast<const float2*>(T + 30 * c + 10 + 10 * b);
        float fs = 0.f;
#pragma unroll
        for (int m = 0; m < 5; ++m) {
            float2 a = pc2[m], e = tc2[m];
            float ce1 = a.x - e.x; ce1 *= ce1;
            float pt1 = fminf(fmaxf(__expf(-ce1), EPSF), 1.0f);
            float o1 = 1.f - pt1;
            fs += o1 * o1 * ce1;
            float ce2 = a.y - e.y; ce2 *= ce2;
            float pt2 = fminf(fmaxf(__expf(-ce2), EPSF), 1.0f);
            float o2 = 1.f - pt2;
            fs += o2 * o2 * ce2;
        }
        if (sig) {
            s4 += fs;
            if (b == 0) s5 += 1.f;
        }
    }

    // ---- reduce: wave shuffle -> LDS across 2 waves -> per-block store ----
    float s[6] = { s0, s1, s2, s3, s4, s5 };
#pragma unroll
    for (int q = 0; q < 6; ++q) s[q] = waveSum(s[q]);
    if (l == 0) {
#pragma unroll
        for (int q = 0; q < 6; ++q) red[w][q] = s[q];
    }
    __syncthreads();
    if (t == 0) {
        float v[6];
#pragma unroll
        for (int q = 0; q < 6; ++q) v[q] = red[0][q] + red[1][q];
        float4* o = reinterpret_cast<float4*>(ws + (size_t)blockIdx.x * 8);
        o[0] = make_float4(v[0], v[1], v[2], v[3]);
        o[1] = make_float4(v[4], v[5], 0.f, 0.f);
    }
}

__global__ __launch_bounds__(256) void yolo_reduce(const float* __restrict__ ws,
                                                   float* __restrict__ out,
                                                   int nBlocks, float invN) {
    float s[6] = {0.f, 0.f, 0.f, 0.f, 0.f, 0.f};
    for (int row = threadIdx.x; row < nBlocks; row += 256) {
        const float4* r4 = reinterpret_cast<const float4*>(ws + (size_t)row * 8);
        float4 a = r4[0], bq = r4[1];
        s[0] += a.x; s[1] += a.y; s[2] += a.z; s[3] += a.w; s[4] += bq.x; s[5] += bq.y;
    }
#pragma unroll
    for (int q = 0; q < 6; ++q) s[q] = waveSum(s[q]);

    __shared__ float red[4][6];
    int lane = threadIdx.x & 63;
    int wv   = threadIdx.x >> 6;
    if (lane == 0) {
#pragma unroll
        for (int q = 0; q < 6; ++q) red[wv][q] = s[q];
    }
    __syncthreads();
    if (threadIdx.x == 0) {
        float obj   = red[0][0] + red[1][0] + red[2][0] + red[3][0];
        float noobj = red[0][1] + red[1][1] + red[2][1] + red[3][1];
        float bboxS = red[0][2] + red[1][2] + red[2][2] + red[3][2];
        float nObj  = red[0][3] + red[1][3] + red[2][3] + red[3][3];
        float clsS  = red[0][4] + red[1][4] + red[2][4] + red[3][4];
        float smS   = red[0][5] + red[1][5] + red[2][5] + red[3][5];

        float bbox_loss = (nObj > 0.f) ? (bboxS / fmaxf(nObj, 1.f)) : 0.f;
        float nCls = smS * (float)NCLS;
        float class_loss = (nCls > 0.f) ? (clsS / fmaxf(nCls, 1.f)) : 0.f;
        float total = obj + L_NOOBJ * noobj + L_COORD * bbox_loss + class_loss;
        out[0] = total * invN;
    }
}

extern "C" void kernel_launch(void* const* d_in, const int* in_sizes, int n_in,
                              void* d_out, int out_size, void* d_ws, size_t ws_size,
                              hipStream_t stream) {
    const float* pred = (const float*)d_in[0];
    const float* targ = (const float*)d_in[1];
    float* out = (float*)d_out;
    float* ws = (float*)d_ws;

    yolo_main<<<NBLOCKS, 128, 0, stream>>>(pred, targ, ws);
    yolo_reduce<<<1, 256, 0, stream>>>(ws, out, NBLOCKS, 1.0f / 4096.0f);
}

// Round 9
// 37.883 us; speedup vs baseline: 1.5677x; 1.0315x over previous
//
#include <hip/hip_runtime.h>
#include <math.h>

// YOLO loss: pred/target (4096,14,14,30) fp32 -> scalar.
// FINAL (= R5, best measured 38.0us): 32-cell tiles, 2 lanes per cell
// (box-split + class-split), per-wave double-buffered global_load_lds with
// counted vmcnt(9), 4-wave blocks @ 61.5KB LDS -> 2 blocks/CU = 8 waves/CU,
// per-block partials + tiny reduce kernel (no same-address atomics).
//
// Why this shape (evidence from R0-R7):
//  - same-address global atomics serialized R0/R1 (184/264us) -> partials+reduce
//  - global_load_lds(16) staging beats VGPR round-trip (R2->R3: 44->40us)
//  - dbuf + counted vmcnt + waves/CU in {4,8,10}: flat 38-40us ->
//    at ~90% of the 6.29 TB/s achievable read ceiling (192.7MB / ~33us kernel)
//  - fused last-block reduction with __threadfence regressed +27us (R6)

#define SGRID 14
#define NCLS 20
#define CELLS_PER_TILE 32
#define F4_PER_INPUT 240         // 32 cells * 30 floats / 4
#define TILE_F4 480              // both inputs
#define NT_TILES 25088           // 802816 cells / 32

constexpr float STEPF  = 1.0f / 14.0f;
constexpr float EPSF   = 1e-7f;
constexpr float L_COORD = 5.0f;
constexpr float L_NOOBJ = 0.5f;

__device__ __forceinline__ float waveSum(float v) {
#pragma unroll
    for (int o = 32; o > 0; o >>= 1) v += __shfl_down(v, o);
    return v;
}

__device__ __forceinline__ void gload_lds16(const void* gsrc, void* ldst) {
    __builtin_amdgcn_global_load_lds(
        (const __attribute__((address_space(1))) void*)gsrc,
        (__attribute__((address_space(3))) void*)ldst, 16, 0, 0);
}
__device__ __forceinline__ void gload_lds4(const void* gsrc, void* ldst) {
    __builtin_amdgcn_global_load_lds(
        (const __attribute__((address_space(1))) void*)gsrc,
        (__attribute__((address_space(3))) void*)ldst, 4, 0, 0);
}

// Stage one 32-cell tile (floats [0..959]=pred, [960..1919]=targ):
// 7 wave-loads of 16B + 2 wave-loads of 4B = 9 vmem ops.
__device__ __forceinline__ void issueTile(const float4* pred4, const float4* targ4,
                                          int tile, int l, float4* dst) {
    const float4* psrc = pred4 + (size_t)tile * F4_PER_INPUT;
    const float4* tsrc = targ4 + (size_t)tile * F4_PER_INPUT;
#pragma unroll
    for (int i = 0; i < 7; ++i) {
        int g = i * 64 + l;
        const float4* src = (g < F4_PER_INPUT) ? (psrc + g) : (tsrc + (g - F4_PER_INPUT));
        gload_lds16(src, dst + i * 64);
    }
    const float* tf = reinterpret_cast<const float*>(tsrc);
    float* df = reinterpret_cast<float*>(dst);
#pragma unroll
    for (int j = 0; j < 2; ++j) {
        gload_lds4(tf + 832 + j * 64 + l, df + 1792 + j * 64);
    }
}

__global__ __launch_bounds__(256, 2) void yolo_main(const float* __restrict__ pred,
                                                    const float* __restrict__ targ,
                                                    float* __restrict__ ws) {
    __shared__ float4 stage[4][2][TILE_F4];   // 61440 B
    __shared__ float red[4][6];

    const int t = threadIdx.x;
    const int w = t >> 6;       // wave in block (0..3)
    const int l = t & 63;       // lane
    const int c = l >> 1;       // cell within tile (0..31)
    const int b = l & 1;        // box index this lane owns

    float s0 = 0.f, s1 = 0.f, s2 = 0.f, s3 = 0.f, s4 = 0.f, s5 = 0.f;

    const int G = gridDim.x * 4;
    const int gwave = blockIdx.x * 4 + w;

    const float4* pred4 = reinterpret_cast<const float4*>(pred);
    const float4* targ4 = reinterpret_cast<const float4*>(targ);

    int buf = 0;
    if (gwave < NT_TILES) issueTile(pred4, targ4, gwave, l, stage[w][0]);

    for (int tile = gwave; tile < NT_TILES; tile += G) {
        const int nxt = tile + G;
        if (nxt < NT_TILES) {
            asm volatile("s_waitcnt lgkmcnt(0)" ::: "memory");
            __builtin_amdgcn_sched_barrier(0);
            issueTile(pred4, targ4, nxt, l, stage[w][buf ^ 1]);
            // wait only for current tile's 9 loads; next tile's 9 stay in flight
            asm volatile("s_waitcnt vmcnt(9)" ::: "memory");
        } else {
            asm volatile("s_waitcnt vmcnt(0)" ::: "memory");
        }
        __builtin_amdgcn_sched_barrier(0);

        const float* P = reinterpret_cast<const float*>(stage[w][buf]);
        const float* T = P + 960;
        buf ^= 1;

        // ---- box phase: lane owns box b of cell c ----
        const float2* p2 = reinterpret_cast<const float2*>(P + 30 * c);
        const float2* t2 = reinterpret_cast<const float2*>(T + 30 * c);
        float2 pA = p2[2 * b], pB = p2[2 * b + 1], pC = p2[2 * b + 2];
        float2 tA = t2[2 * b], tB = t2[2 * b + 1], tC = t2[2 * b + 2];
        float t9v = (T + 30 * c)[9];
        float p0 = b ? pA.y : pA.x;
        float p1 = b ? pB.x : pA.y;
        float p2f = b ? pB.y : pB.x;
        float p3f = b ? pC.x : pB.y;
        float p4f = b ? pC.y : pC.x;
        float t0 = b ? tA.y : tA.x;
        float t1 = b ? tB.x : tA.y;
        float t2f = b ? tB.y : tB.x;
        float t3f = b ? tC.x : tB.y;
        float t4f = b ? tC.y : tC.x;

        int cell = tile * CELLS_PER_TILE + c;     // layout (n, jy, ix)
        float ix = (float)(cell % SGRID);
        float jy = (float)((cell / SGRID) % SGRID);

        // paired IOU (cell-converted) for argmax
        float px = fmaxf((p0 + ix) * STEPF - p2f * 0.5f, 0.f);
        float py = fmaxf((p1 + jy) * STEPF - p3f * 0.5f, 0.f);
        float pw = fmaxf(p2f, 0.f), ph = fmaxf(p3f, 0.f);
        float tx = fmaxf((t0 + ix) * STEPF - t2f * 0.5f, 0.f);
        float ty = fmaxf((t1 + jy) * STEPF - t3f * 0.5f, 0.f);
        float tw = fmaxf(t2f, 0.f), th = fmaxf(t3f, 0.f);
        float iw = pw + tw - (fmaxf(px + pw, tx + tw) - fminf(px, tx));
        float ih = ph + th - (fmaxf(py + ph, ty + th) - fminf(py, ty));
        float inter0 = fmaxf(iw, 0.f) * fmaxf(ih, 0.f);
        float iouP = inter0 / (pw * ph + tw * th - inter0 + EPSF);

        float other = __shfl_xor(iouP, 1);
        float i0 = b ? other : iouP;
        float i1 = b ? iouP : other;
        int maxi = (i1 > i0) ? 1 : 0;             // jnp.argmax: ties -> 0
        bool sig = t9v > 0.f;
        bool om = t4f > 0.f;
        bool kp = (!sig) || (b == maxi);
        float f = (om && kp) ? 1.f : 0.f;

        float d = p4f - t4f;
        float d2 = d * d;
        s0 += f * d2;
        s1 += (1.f - f) * d2;

        // DIoU on raw xywh -> xyxy
        float px1 = p0 - p2f * 0.5f, py1 = p1 - p3f * 0.5f;
        float px2 = p0 + p2f * 0.5f, py2 = p1 + p3f * 0.5f;
        float tx1 = t0 - t2f * 0.5f, ty1 = t1 - t3f * 0.5f;
        float tx2 = t0 + t2f * 0.5f, ty2 = t1 + t3f * 0.5f;

        float xi1 = fmaxf(px1, tx1), yi1 = fmaxf(py1, ty1);
        float xi2 = fminf(px2, tx2), yi2 = fminf(py2, ty2);
        float inter = fmaxf(xi2 - xi1, 0.f) * fmaxf(yi2 - yi1, 0.f);
        float a1 = fmaxf(px2 - px1, 0.f) * fmaxf(py2 - py1, 0.f);
        float a2 = fmaxf(tx2 - tx1, 0.f) * fmaxf(ty2 - ty1, 0.f);
        float iou = fmaxf(inter / (a1 + a2 - inter + EPSF), EPSF);

        float pcx = (px1 + px2) * 0.5f, pcy = (py1 + py2) * 0.5f;
        float tcx = (tx1 + tx2) * 0.5f, tcy = (ty1 + ty2) * 0.5f;
        float cd = (pcx - tcx) * (pcx - tcx) + (pcy - tcy) * (pcy - tcy);
        float ex1 = fminf(px1, tx1), ey1 = fminf(py1, ty1);
        float ex2 = fmaxf(px2, tx2), ey2 = fmaxf(py2, ty2);
        float diag = (ex2 - ex1) * (ex2 - ex1) + (ey2 - ey1) * (ey2 - ey1) + EPSF;
        float diou = 1.f - sqrtf(iou) + cd / diag;

        s2 += f * diou;
        s3 += f;

        // ---- class phase: lane handles 10 channels (10b..10b+9) of cell c ----
        const float2* pc2 = reinterpret_cast<const float2*>(P + 30 * c + 10 + 10 * b);
        const float2* tc2 = reinterpret_cast<const float2*>(T + 30 * c + 10 + 10 * b);
        float fs = 0.f;
#pragma unroll
        for (int m = 0; m < 5; ++m) {
            float2 a = pc2[m], e = tc2[m];
            float ce1 = a.x - e.x; ce1 *= ce1;
            float pt1 = fminf(fmaxf(__expf(-ce1), EPSF), 1.0f);
            float o1 = 1.f - pt1;
            fs += o1 * o1 * ce1;
            float ce2 = a.y - e.y; ce2 *= ce2;
            float pt2 = fminf(fmaxf(__expf(-ce2), EPSF), 1.0f);
            float o2 = 1.f - pt2;
            fs += o2 * o2 * ce2;
        }
        if (sig) {
            s4 += fs;
            if (b == 0) s5 += 1.f;
        }
    }

    // ---- reduce: wave shuffle -> LDS across 4 waves -> per-block store ----
    float s[6] = { s0, s1, s2, s3, s4, s5 };
#pragma unroll
    for (int q = 0; q < 6; ++q) s[q] = waveSum(s[q]);
    if (l == 0) {
#pragma unroll
        for (int q = 0; q < 6; ++q) red[w][q] = s[q];
    }
    __syncthreads();
    if (t == 0) {
        float v[6];
#pragma unroll
        for (int q = 0; q < 6; ++q) v[q] = red[0][q] + red[1][q] + red[2][q] + red[3][q];
        float4* o = reinterpret_cast<float4*>(ws + (size_t)blockIdx.x * 8);
        o[0] = make_float4(v[0], v[1], v[2], v[3]);
        o[1] = make_float4(v[4], v[5], 0.f, 0.f);
    }
}

__global__ __launch_bounds__(256) void yolo_reduce(const float* __restrict__ ws,
                                                   float* __restrict__ out,
                                                   int nBlocks, float invN) {
    float s[6] = {0.f, 0.f, 0.f, 0.f, 0.f, 0.f};
    for (int row = threadIdx.x; row < nBlocks; row += 256) {
        const float4* r4 = reinterpret_cast<const float4*>(ws + (size_t)row * 8);
        float4 a = r4[0], bq = r4[1];
        s[0] += a.x; s[1] += a.y; s[2] += a.z; s[3] += a.w; s[4] += bq.x; s[5] += bq.y;
    }
#pragma unroll
    for (int q = 0; q < 6; ++q) s[q] = waveSum(s[q]);

    __shared__ float red[4][6];
    int lane = threadIdx.x & 63;
    int wv   = threadIdx.x >> 6;
    if (lane == 0) {
#pragma unroll
        for (int q = 0; q < 6; ++q) red[wv][q] = s[q];
    }
    __syncthreads();
    if (threadIdx.x == 0) {
        float obj   = red[0][0] + red[1][0] + red[2][0] + red[3][0];
        float noobj = red[0][1] + red[1][1] + red[2][1] + red[3][1];
        float bboxS = red[0][2] + red[1][2] + red[2][2] + red[3][2];
        float nObj  = red[0][3] + red[1][3] + red[2][3] + red[3][3];
        float clsS  = red[0][4] + red[1][4] + red[2][4] + red[3][4];
        float smS   = red[0][5] + red[1][5] + red[2][5] + red[3][5];

        float bbox_loss = (nObj > 0.f) ? (bboxS / fmaxf(nObj, 1.f)) : 0.f;
        float nCls = smS * (float)NCLS;
        float class_loss = (nCls > 0.f) ? (clsS / fmaxf(nCls, 1.f)) : 0.f;
        float total = obj + L_NOOBJ * noobj + L_COORD * bbox_loss + class_loss;
        out[0] = total * invN;
    }
}

extern "C" void kernel_launch(void* const* d_in, const int* in_sizes, int n_in,
                              void* d_out, int out_size, void* d_ws, size_t ws_size,
                              hipStream_t stream) {
    const float* pred = (const float*)d_in[0];
    const float* targ = (const float*)d_in[1];
    float* out = (float*)d_out;
    float* ws = (float*)d_ws;

    int blocks = 512;   // 4 waves each, 61.5KB LDS -> 2 blocks/CU = 8 waves/CU

    yolo_main<<<blocks, 256, 0, stream>>>(pred, targ, ws);
    yolo_reduce<<<1, 256, 0, stream>>>(ws, out, blocks, 1.0f / 4096.0f);
}